// Round 8
// baseline (383.945 us; speedup 1.0000x reference)
//
#include <hip/hip_runtime.h>
#include <hip/hip_cooperative_groups.h>
#include <math.h>

namespace cg = cooperative_groups;

#define N_ROWS 8192
#define D_DIM  512
#define C_CLS  100
#define GRID   256
#define BLK    1024

typedef unsigned short u16;
typedef unsigned int u32;
typedef __attribute__((ext_vector_type(8))) short short8;
typedef __attribute__((ext_vector_type(4))) float floatx4;

// ---------------- ws layout (float offsets), ~33.8 MB ----------------
#define WS_G      0              // 512*512
#define WS_GP     262144         // 16*10 * 128*128 upper-tile partials
#define WS_INV    2883584        // 8192
#define WS_SINV   2891776        // 8192
#define WS_WV     2899968        // 8192
#define WS_CLS    2908160        // 8192 (int)
#define WS_CNT    2916352        // 128 (int)
#define WS_UP     2916480        // 12*8*6400 u partials
#define WS_VP     3530880        // 12*8*6400 v partials
#define WS_U      4145280        // 100*512
#define WS_V      4196480        // 100*512
#define WS_ZTH    4247680        // 512*8192 u16
#define WS_ZTL    6344832

#define LDT 65
#define UV_SLICES 12
#define UV_ROWS 683              // ceil(8192/12)

struct SMem {
    union {
        struct { u16 Ah[128*32], Al[128*32], Bh[128*32], Bl[128*32]; } g; // 32 KB
        unsigned zt[2][64 * LDT];                                         // 33.3 KB
        struct { float us[C_CLS * 64], vs[C_CLS * 64]; } uv;              // 51.2 KB
        float ug[D_DIM];
    };
};

// split fp32 -> bf16 hi (chop) + bf16 lo (chop of remainder); rel err ~2^-16
__device__ __forceinline__ void split2(float v, u16& h, u16& l) {
    unsigned u = __float_as_uint(v);
    h = (u16)(u >> 16);
    float r = v - __uint_as_float(u & 0xFFFF0000u);
    l = (u16)(__float_as_uint(r) >> 16);
}

typedef const __attribute__((address_space(1))) u32* gp32;
typedef __attribute__((address_space(3))) u32* lp32;
__device__ __forceinline__ void cp16(const u16* g, u16* l) {
    __builtin_amdgcn_global_load_lds((gp32)g, (lp32)l, 16, 0, 0);
}

// ========== P1: softmax stats + row norms (wave per row) ==========
__device__ void phase_prep(int bx, int t, const float* __restrict__ logits,
        const float* __restrict__ x, float* __restrict__ wv,
        int* __restrict__ cls, float* __restrict__ inv, float* __restrict__ sinv) {
    int gwave = (bx << 4) + (t >> 6);          // 0..4095
    int lane = t & 63;
    for (int row = gwave; row < N_ROWS; row += 4096) {
        const float* lrow = logits + (size_t)row * C_CLS;
        float v1 = lrow[lane];
        bool has2 = (lane + 64) < C_CLS;
        float v2 = has2 ? lrow[lane + 64] : -INFINITY;
        float m; int idx;
        if (v2 > v1) { m = v2; idx = lane + 64; } else { m = v1; idx = lane; }
        #pragma unroll
        for (int off = 32; off >= 1; off >>= 1) {
            float om = __shfl_down(m, off);
            int   oi = __shfl_down(idx, off);
            if (om > m || (om == m && oi < idx)) { m = om; idx = oi; }
        }
        m = __shfl(m, 0);
        idx = __shfl(idx, 0);
        float s = expf(v1 - m) + (has2 ? expf(v2 - m) : 0.0f);
        #pragma unroll
        for (int off = 32; off >= 1; off >>= 1) s += __shfl_down(s, off);
        const float* xr = x + (size_t)row * D_DIM;
        float ss = 0.f;
        #pragma unroll
        for (int j = 0; j < D_DIM; j += 64) {
            float v = xr[j + lane];
            ss += v * v;
        }
        #pragma unroll
        for (int off = 32; off >= 1; off >>= 1) ss += __shfl_down(ss, off);
        if (lane == 0) {
            wv[row] = 1.0f / s;
            cls[row] = idx;
            float iv = 1.0f / fmaxf(sqrtf(ss), 1e-8f);
            inv[row] = iv;
            sinv[row] = sqrtf(iv);
        }
    }
}

// ========== P2: split+transpose z (2 tiles/block/round, 2 rounds) + hist ==
__device__ void phase_mid(SMem& sm, int* hist, int bx, int t,
        const float* __restrict__ x, const float* __restrict__ sinv,
        const int* __restrict__ cls, u16* __restrict__ zth, u16* __restrict__ ztl,
        int* __restrict__ cnt) {
    int h = t >> 9, tt = t & 511;
    #pragma unroll
    for (int round = 0; round < 2; ++round) {
        int tile = (bx << 1) + h + (round << 9);    // 0..1023
        int r0 = (tile & 127) << 6, c0 = (tile >> 7) << 6;
        int r = tt >> 3, cq = tt & 7;
        const float* src = x + (size_t)(r0 + r) * D_DIM + c0 + cq * 8;
        float vv[8];
        {
            float4 a = *(const float4*)(src + 0);
            float4 b = *(const float4*)(src + 4);
            vv[0]=a.x; vv[1]=a.y; vv[2]=a.z; vv[3]=a.w;
            vv[4]=b.x; vv[5]=b.y; vv[6]=b.z; vv[7]=b.w;
        }
        float sv = sinv[r0 + r];
        #pragma unroll
        for (int j = 0; j < 8; ++j) {
            u16 hh, ll;
            split2(sv * vv[j], hh, ll);
            sm.zt[h][(cq * 8 + j) * LDT + r] = ((unsigned)hh << 16) | ll;
        }
        __syncthreads();
        int c = tt >> 3, rq = (tt & 7) * 8;
        size_t tbase = (size_t)(c0 + c) * N_ROWS + r0 + rq;
        uint oh[4], ol[4];
        #pragma unroll
        for (int p = 0; p < 4; ++p) {
            unsigned d0 = sm.zt[h][c * LDT + rq + 2*p];
            unsigned d1 = sm.zt[h][c * LDT + rq + 2*p + 1];
            oh[p] = (d0 >> 16) | (d1 & 0xFFFF0000u);
            ol[p] = (d0 & 0xFFFFu) | (d1 << 16);
        }
        *(uint4*)&zth[tbase] = make_uint4(oh[0], oh[1], oh[2], oh[3]);
        *(uint4*)&ztl[tbase] = make_uint4(ol[0], ol[1], ol[2], ol[3]);
        __syncthreads();
    }
    if (bx == GRID - 1) {
        if (t < 128) hist[t] = 0;
        __syncthreads();
        for (int m2 = t; m2 < N_ROWS; m2 += BLK) atomicAdd(&hist[cls[m2]], 1);
        __syncthreads();
        if (t < 128) cnt[t] = hist[t];
    }
}

// ====== P3: blocks 0..159 GEMM (splitK=16); blocks 160..255 uv-LDS ======
__device__ void phase_big(SMem& sm, int bx, int t, const u16* __restrict__ zth,
        const u16* __restrict__ ztl, const float* __restrict__ x,
        const float* __restrict__ inv, const float* __restrict__ wv,
        const int* __restrict__ cls, float* __restrict__ Gp,
        float* __restrict__ up, float* __restrict__ vp) {
    if (bx < 160) {
        int tile = bx % 10;
        int p = bx / 10;                    // 0..15
        int ti = tile < 4 ? 0 : (tile < 7 ? 1 : (tile < 9 ? 2 : 3));
        int tj = tile - (ti == 0 ? 0 : (ti == 1 ? 3 : (ti == 2 ? 5 : 6)));
        int i0 = ti << 7, j0 = tj << 7;
        bool diag = (ti == tj);
        int kb = p << 9;                    // K-chunk of 512
        int w = t >> 6, l = t & 63;
        int wr = w >> 2, wc = w & 3;
        int lm = l & 15, lg = l >> 4;
        floatx4 acc[2][2];
        #pragma unroll
        for (int mi = 0; mi < 2; ++mi)
            #pragma unroll
            for (int ni = 0; ni < 2; ++ni) acc[mi][ni] = (floatx4){0.f,0.f,0.f,0.f};
        int tq = t & 511;
        int srow = tq >> 2, scol = (tq & 3) << 3;
        int dst = srow * 32 + scol;
        bool isA = (t < 512);
        const size_t gA = (size_t)(i0 + srow) * N_ROWS + kb + scol;
        const size_t gB = (size_t)(j0 + srow) * N_ROWS + kb + scol;
        const u16* Bhs = diag ? sm.g.Ah : sm.g.Bh;
        const u16* Bls = diag ? sm.g.Al : sm.g.Bl;
        for (int s = 0; s < 16; ++s) {
            int ks = s << 5;
            if (isA) {
                cp16(zth + gA + ks, sm.g.Ah + dst);
                cp16(ztl + gA + ks, sm.g.Al + dst);
            } else if (!diag) {
                cp16(zth + gB + ks, sm.g.Bh + dst);
                cp16(ztl + gB + ks, sm.g.Bl + dst);
            }
            __syncthreads();
            short8 ah[2], al[2], bh[2], bl[2];
            #pragma unroll
            for (int mi = 0; mi < 2; ++mi) {
                int off = ((wr << 5) + (mi << 4) + lm) * 32 + (lg << 3);
                ah[mi] = *(const short8*)&sm.g.Ah[off];
                al[mi] = *(const short8*)&sm.g.Al[off];
            }
            #pragma unroll
            for (int ni = 0; ni < 2; ++ni) {
                int off = ((wc << 5) + (ni << 4) + lm) * 32 + (lg << 3);
                bh[ni] = *(const short8*)&Bhs[off];
                bl[ni] = *(const short8*)&Bls[off];
            }
            #pragma unroll
            for (int mi = 0; mi < 2; ++mi)
                #pragma unroll
                for (int ni = 0; ni < 2; ++ni) {
                    acc[mi][ni] = __builtin_amdgcn_mfma_f32_16x16x32_bf16(ah[mi], bh[ni], acc[mi][ni], 0, 0, 0);
                    acc[mi][ni] = __builtin_amdgcn_mfma_f32_16x16x32_bf16(ah[mi], bl[ni], acc[mi][ni], 0, 0, 0);
                    acc[mi][ni] = __builtin_amdgcn_mfma_f32_16x16x32_bf16(al[mi], bh[ni], acc[mi][ni], 0, 0, 0);
                }
            __syncthreads();
        }
        float* Gb = Gp + ((size_t)(p * 10 + tile) << 14);
        #pragma unroll
        for (int mi = 0; mi < 2; ++mi) {
            int row0 = (wr << 5) + (mi << 4) + (lg << 2);
            #pragma unroll
            for (int ni = 0; ni < 2; ++ni) {
                int col = (wc << 5) + (ni << 4) + lm;
                #pragma unroll
                for (int r = 0; r < 4; ++r)
                    Gb[(size_t)(row0 + r) * 128 + col] = acc[mi][ni][r];
            }
        }
    } else {
        int idx = bx - 160;                 // 0..95
        int rs = idx >> 3, jc = idx & 7;    // rs 0..11
        int lo = rs * UV_ROWS;
        int hi = min(N_ROWS, lo + UV_ROWS);
        for (int k = t; k < C_CLS * 64; k += BLK) {
            sm.uv.us[k] = 0.f;
            sm.uv.vs[k] = 0.f;
        }
        __syncthreads();
        int w = t >> 6, l = t & 63;
        int j = jc * 64 + l;
        for (int m = lo + w; m < hi; m += 16) {
            int c = cls[m];
            float wm = wv[m];
            float wi = wm * inv[m];
            float xv = x[(size_t)m * D_DIM + j];
            atomicAdd(&sm.uv.us[c * 64 + l], wi * xv);
            atomicAdd(&sm.uv.vs[c * 64 + l], wm * xv);
        }
        __syncthreads();
        size_t base = (size_t)(rs * 8 + jc) * (C_CLS * 64);
        for (int k = t; k < C_CLS * 64; k += BLK) {
            up[base + k] = sm.uv.us[k];
            vp[base + k] = sm.uv.vs[k];
        }
    }
}

// ====== P4: reduce G partials (mirror) + reduce uv partials ======
__device__ void phase_reduceG(int bx, int t, const float* __restrict__ Gp,
        const float* __restrict__ up, const float* __restrict__ vp,
        float* __restrict__ G, float* __restrict__ u_arr, float* __restrict__ v_arr) {
    {
        int i = bx * BLK + t;              // exactly 262144 = 512*512
        int r = i >> 9, c = i & 511;
        int tr = r >> 7, tc = c >> 7, rr = r & 127, cc = c & 127;
        if (tr > tc) { int tmp = tr; tr = tc; tc = tmp; tmp = rr; rr = cc; cc = tmp; }
        int tid = tr * 4 + tc - ((tr * (tr + 1)) >> 1);
        const float* src = Gp + ((size_t)tid << 14) + rr * 128 + cc;
        float ssum = 0.f;
        #pragma unroll
        for (int p = 0; p < 16; ++p) ssum += src[(size_t)p * 163840];
        G[i] = ssum;
    }
    if (bx < 25) {
        #pragma unroll
        for (int k = 0; k < 4; ++k) {
            int eid = bx * 4096 + k * 1024 + t;    // 0..102399
            int e = (eid < C_CLS * D_DIM) ? eid : eid - C_CLS * D_DIM;
            int c = e >> 9, jj = e & 511;
            int jc = jj >> 6, l = jj & 63;
            const float* src = (eid < C_CLS * D_DIM ? up : vp);
            float ssum = 0.f;
            #pragma unroll
            for (int rs = 0; rs < UV_SLICES; ++rs)
                ssum += src[(size_t)(rs * 8 + jc) * (C_CLS * 64) + c * 64 + l];
            if (eid < C_CLS * D_DIM) u_arr[e] = ssum;
            else                     v_arr[e] = ssum;
        }
    }
}

// ====== P5: protos = (v + u@G) / n -> out[0:51200) ======
__device__ void phase_pgemm(SMem& sm, int bx, int t, const float* __restrict__ u_arr,
        const float* __restrict__ v_arr, const int* __restrict__ cnt,
        const float* __restrict__ G, float* __restrict__ out) {
    if (bx >= C_CLS) return;
    int c = bx;
    if (t < D_DIM) sm.ug[t] = u_arr[(size_t)c * D_DIM + t];
    __syncthreads();
    if (t < D_DIM) {
        float acc = v_arr[(size_t)c * D_DIM + t];
        #pragma unroll 8
        for (int k = 0; k < D_DIM; ++k)
            acc += sm.ug[k] * G[(size_t)k * D_DIM + t];
        int n = cnt[c];
        float s = (n > 0) ? 1.0f / (float)n : 0.0f;
        out[(size_t)c * D_DIM + t] = acc * s;
    }
}

// ====== P6: inter[i,j,:] = proto[j] - proto[i] ======
__device__ void phase_inter(int bx, int t, const float* __restrict__ proto,
                            float* __restrict__ inter) {
    for (int idx = bx * BLK + t; idx < C_CLS * C_CLS * 128; idx += GRID * BLK) {
        int pair = idx >> 7;
        int d = (idx & 127) << 2;
        int i = pair / C_CLS;
        int j = pair - i * C_CLS;
        float4 pj = *(const float4*)&proto[j * D_DIM + d];
        float4 pi = *(const float4*)&proto[i * D_DIM + d];
        float4 r;
        r.x = pj.x - pi.x; r.y = pj.y - pi.y; r.z = pj.z - pi.z; r.w = pj.w - pi.w;
        *(float4*)&inter[(size_t)pair * D_DIM + d] = r;
    }
}

// ================= fused cooperative mega-kernel =======================
__global__ __launch_bounds__(BLK, 4) void k_all(
        const float* __restrict__ x, const float* __restrict__ logits,
        float* __restrict__ wv, int* __restrict__ cls,
        float* __restrict__ inv, float* __restrict__ sinv,
        u16* __restrict__ zth, u16* __restrict__ ztl,
        int* __restrict__ cnt, float* __restrict__ Gp,
        float* __restrict__ up, float* __restrict__ vp,
        float* __restrict__ u_arr, float* __restrict__ v_arr,
        float* __restrict__ G, float* __restrict__ out) {
    cg::grid_group grid = cg::this_grid();
    __shared__ SMem sm;
    __shared__ int hist[128];
    int bx = blockIdx.x, t = threadIdx.x;
    phase_prep(bx, t, logits, x, wv, cls, inv, sinv);
    grid.sync();
    phase_mid(sm, hist, bx, t, x, sinv, cls, zth, ztl, cnt);
    grid.sync();
    phase_big(sm, bx, t, zth, ztl, x, inv, wv, cls, Gp, up, vp);
    grid.sync();
    phase_reduceG(bx, t, Gp, up, vp, G, u_arr, v_arr);
    grid.sync();
    phase_pgemm(sm, bx, t, u_arr, v_arr, cnt, G, out);
    grid.sync();
    phase_inter(bx, t, out, out + C_CLS * D_DIM);
}

// ================= fallback per-phase kernels ==========================
__global__ __launch_bounds__(BLK) void k_p1(const float* x, const float* logits,
        float* wv, int* cls, float* inv, float* sinv) {
    phase_prep(blockIdx.x, threadIdx.x, logits, x, wv, cls, inv, sinv);
}
__global__ __launch_bounds__(BLK) void k_p2(const float* x, const float* sinv,
        const int* cls, u16* zth, u16* ztl, int* cnt) {
    __shared__ SMem sm;
    __shared__ int hist[128];
    phase_mid(sm, hist, blockIdx.x, threadIdx.x, x, sinv, cls, zth, ztl, cnt);
}
__global__ __launch_bounds__(BLK) void k_p3(const u16* zth, const u16* ztl,
        const float* x, const float* inv, const float* wv, const int* cls,
        float* Gp, float* up, float* vp) {
    __shared__ SMem sm;
    phase_big(sm, blockIdx.x, threadIdx.x, zth, ztl, x, inv, wv, cls, Gp, up, vp);
}
__global__ __launch_bounds__(BLK) void k_p4(const float* Gp, const float* up,
        const float* vp, float* G, float* u_arr, float* v_arr) {
    phase_reduceG(blockIdx.x, threadIdx.x, Gp, up, vp, G, u_arr, v_arr);
}
__global__ __launch_bounds__(BLK) void k_p5(const float* u_arr, const float* v_arr,
        const int* cnt, const float* G, float* out) {
    __shared__ SMem sm;
    phase_pgemm(sm, blockIdx.x, threadIdx.x, u_arr, v_arr, cnt, G, out);
}
__global__ __launch_bounds__(BLK) void k_p6(const float* proto, float* inter) {
    phase_inter(blockIdx.x, threadIdx.x, proto, inter);
}

extern "C" void kernel_launch(void* const* d_in, const int* in_sizes, int n_in,
                              void* d_out, int out_size, void* d_ws, size_t ws_size,
                              hipStream_t stream) {
    const float* x      = (const float*)d_in[0];   // [8192, 512]
    const float* logits = (const float*)d_in[1];   // [8192, 100]
    float* out = (float*)d_out;
    float* ws  = (float*)d_ws;
    float* G     = ws + WS_G;
    float* Gp    = ws + WS_GP;
    float* inv   = ws + WS_INV;
    float* sinv  = ws + WS_SINV;
    float* wv    = ws + WS_WV;
    int*   cls   = (int*)(ws + WS_CLS);
    int*   cnt   = (int*)(ws + WS_CNT);
    float* up    = ws + WS_UP;
    float* vp    = ws + WS_VP;
    float* u_arr = ws + WS_U;
    float* v_arr = ws + WS_V;
    u16* zth = (u16*)(ws + WS_ZTH);
    u16* ztl = (u16*)(ws + WS_ZTL);

    void* args[] = {
        (void*)&x, (void*)&logits, (void*)&wv, (void*)&cls, (void*)&inv,
        (void*)&sinv, (void*)&zth, (void*)&ztl, (void*)&cnt, (void*)&Gp,
        (void*)&up, (void*)&vp, (void*)&u_arr, (void*)&v_arr, (void*)&G,
        (void*)&out
    };
    hipError_t err = hipLaunchCooperativeKernel((void*)k_all, dim3(GRID), dim3(BLK),
                                                args, 0, stream);
    if (err != hipSuccess) {
        k_p1<<<GRID, BLK, 0, stream>>>(x, logits, wv, cls, inv, sinv);
        k_p2<<<GRID, BLK, 0, stream>>>(x, sinv, cls, zth, ztl, cnt);
        k_p3<<<GRID, BLK, 0, stream>>>(zth, ztl, x, inv, wv, cls, Gp, up, vp);
        k_p4<<<GRID, BLK, 0, stream>>>(Gp, up, vp, G, u_arr, v_arr);
        k_p5<<<GRID, BLK, 0, stream>>>(u_arr, v_arr, cnt, G, out);
        k_p6<<<GRID, BLK, 0, stream>>>(out, out + C_CLS * D_DIM);
    }
}

// Round 9
// 185.629 us; speedup vs baseline: 2.0683x; 2.0683x over previous
//
#include <hip/hip_runtime.h>
#include <math.h>

#define N_ROWS 8192
#define D_DIM  512
#define C_CLS  100

typedef unsigned short u16;
typedef unsigned int u32;
typedef __attribute__((ext_vector_type(8))) short short8;
typedef __attribute__((ext_vector_type(4))) float floatx4;

// ---------------- ws layout (float offsets), ~18.4 MB ----------------
#define WS_G      0              // 512*512 (atomic accumulated, zeroed in kA)
#define WS_INV    262144         // 8192
#define WS_WV     270336         // 8192
#define WS_CLS    278528         // 8192 (int)
#define WS_CNT    286720         // 128 (int)
#define WS_OFFS   286848         // 128 (int)
#define WS_ORDER  286976         // 8192 (int)
#define WS_U      295168         // 100*512
#define WS_V      346368         // 100*512
#define WS_ZTH    397568         // 512*8192 u16
#define WS_ZTL    2494720

#define LDT 65

// split fp32 -> bf16 hi (chop) + bf16 lo (chop of remainder); rel err ~2^-16
__device__ __forceinline__ void split2(float v, u16& h, u16& l) {
    unsigned u = __float_as_uint(v);
    h = (u16)(u >> 16);
    float r = v - __uint_as_float(u & 0xFFFF0000u);
    l = (u16)(__float_as_uint(r) >> 16);
}

typedef const __attribute__((address_space(1))) u32* gp32;
typedef __attribute__((address_space(3))) u32* lp32;
__device__ __forceinline__ void cp16(const u16* g, u16* l) {
    __builtin_amdgcn_global_load_lds((gp32)g, (lp32)l, 16, 0, 0);
}

// ===== kA: bx<2048 softmax | bx in [2048,2176) norm+split+transpose | rest zero G
__global__ __launch_bounds__(256) void kA(const float* __restrict__ logits,
        const float* __restrict__ x, float* __restrict__ wv, int* __restrict__ cls,
        float* __restrict__ inv, u16* __restrict__ zth, u16* __restrict__ ztl,
        float* __restrict__ G) {
    __shared__ unsigned zt_p[64 * LDT];
    __shared__ float ns[4][64];
    __shared__ float sv_s[64];
    int bx = blockIdx.x, t = threadIdx.x;
    if (bx < 2048) {
        // -------- softmax max/argmax/denom, one wave per row --------
        int row = (bx << 2) + (t >> 6);
        int lane = t & 63;
        const float* lrow = logits + (size_t)row * C_CLS;
        float v1 = lrow[lane];
        bool has2 = (lane + 64) < C_CLS;
        float v2 = has2 ? lrow[lane + 64] : -INFINITY;
        float m; int idx;
        if (v2 > v1) { m = v2; idx = lane + 64; } else { m = v1; idx = lane; }
        #pragma unroll
        for (int off = 32; off >= 1; off >>= 1) {
            float om = __shfl_down(m, off);
            int   oi = __shfl_down(idx, off);
            if (om > m || (om == m && oi < idx)) { m = om; idx = oi; }
        }
        m = __shfl(m, 0);
        idx = __shfl(idx, 0);
        float s = expf(v1 - m) + (has2 ? expf(v2 - m) : 0.0f);
        #pragma unroll
        for (int off = 32; off >= 1; off >>= 1) s += __shfl_down(s, off);
        if (lane == 0) {
            wv[row] = 1.0f / s;       // max softmax prob = 1/denom
            cls[row] = idx;
        }
        return;
    }
    if (bx >= 2176) {
        // -------- zero G: 32 blocks x 256 thr x 32 floats --------
        int i = ((bx - 2176) * 256 + t) * 32;
        float4 z = make_float4(0.f, 0.f, 0.f, 0.f);
        #pragma unroll
        for (int q = 0; q < 8; ++q) *(float4*)&G[i + q * 4] = z;
        return;
    }
    // -------- norm + split + transpose for 64-row stripe --------
    int r0 = (bx - 2048) << 6;
    {
        int l = t & 63, q = t >> 6;
        const float* src = x + (size_t)(r0 + l) * D_DIM + q * 128;
        float ss = 0.f;
        #pragma unroll
        for (int i = 0; i < 32; ++i) {
            float4 v = *(const float4*)(src + i * 4);
            ss += v.x * v.x + v.y * v.y + v.z * v.z + v.w * v.w;
        }
        ns[q][l] = ss;
    }
    __syncthreads();
    if (t < 64) {
        float ss = ns[0][t] + ns[1][t] + ns[2][t] + ns[3][t];
        float iv = 1.0f / fmaxf(sqrtf(ss), 1e-8f);
        inv[r0 + t] = iv;
        sv_s[t] = sqrtf(iv);
    }
    __syncthreads();
    for (int ct = 0; ct < 8; ++ct) {
        int c0 = ct * 64;
        int r = t >> 2, cq = t & 3;
        const float* src = x + (size_t)(r0 + r) * D_DIM + c0 + cq * 16;
        float vv[16];
        {
            float4 a = *(const float4*)(src + 0);
            float4 b = *(const float4*)(src + 4);
            float4 c = *(const float4*)(src + 8);
            float4 d = *(const float4*)(src + 12);
            vv[0]=a.x; vv[1]=a.y; vv[2]=a.z; vv[3]=a.w;
            vv[4]=b.x; vv[5]=b.y; vv[6]=b.z; vv[7]=b.w;
            vv[8]=c.x; vv[9]=c.y; vv[10]=c.z; vv[11]=c.w;
            vv[12]=d.x; vv[13]=d.y; vv[14]=d.z; vv[15]=d.w;
        }
        float sv = sv_s[r];
        #pragma unroll
        for (int j = 0; j < 16; ++j) {
            u16 h, l;
            split2(sv * vv[j], h, l);
            zt_p[(cq * 16 + j) * LDT + r] = ((unsigned)h << 16) | l;
        }
        __syncthreads();
        int c = t >> 2, rq = (t & 3) * 16;
        size_t tbase = (size_t)(c0 + c) * N_ROWS + r0 + rq;
        uint oh[8], ol[8];
        #pragma unroll
        for (int p = 0; p < 8; ++p) {
            unsigned d0 = zt_p[c * LDT + rq + 2*p];
            unsigned d1 = zt_p[c * LDT + rq + 2*p + 1];
            oh[p] = (d0 >> 16) | (d1 & 0xFFFF0000u);
            ol[p] = (d0 & 0xFFFFu) | (d1 << 16);
        }
        *(uint4*)&zth[tbase]     = make_uint4(oh[0], oh[1], oh[2], oh[3]);
        *(uint4*)&zth[tbase + 8] = make_uint4(oh[4], oh[5], oh[6], oh[7]);
        *(uint4*)&ztl[tbase]     = make_uint4(ol[0], ol[1], ol[2], ol[3]);
        *(uint4*)&ztl[tbase + 8] = make_uint4(ol[4], ol[5], ol[6], ol[7]);
        __syncthreads();
    }
}

// ===== kB: single-block class histogram + scan + scatter =====
__global__ __launch_bounds__(256) void kB(const int* __restrict__ cls,
        int* __restrict__ cnt, int* __restrict__ offs, int* __restrict__ order) {
    __shared__ int hist[128], scan_s[128], cur[128];
    int t = threadIdx.x;
    if (t < 128) hist[t] = 0;
    __syncthreads();
    for (int m = t; m < N_ROWS; m += 256) atomicAdd(&hist[cls[m]], 1);
    __syncthreads();
    if (t < 128) scan_s[t] = hist[t];
    __syncthreads();
    #pragma unroll
    for (int d = 1; d < 128; d <<= 1) {
        int add = (t < 128 && t >= d) ? scan_s[t - d] : 0;
        __syncthreads();
        if (t < 128) scan_s[t] += add;
        __syncthreads();
    }
    if (t < 128) {
        int off0 = scan_s[t] - hist[t];
        cur[t] = off0;
        offs[t] = off0;
        cnt[t] = hist[t];
    }
    __syncthreads();
    for (int m = t; m < N_ROWS; m += 256) {
        int p = atomicAdd(&cur[cls[m]], 1);
        order[p] = m;
    }
}

// ===== kC: blocks 0..159 GEMM (splitK=16, atomic G + mirror); 160..959 uv ===
__global__ __launch_bounds__(256) void kC(const u16* __restrict__ zth,
        const u16* __restrict__ ztl, const float* __restrict__ x,
        const float* __restrict__ inv, const float* __restrict__ wv,
        const int* __restrict__ order, const int* __restrict__ offs,
        const int* __restrict__ cnt, float* __restrict__ G,
        float* __restrict__ u_arr, float* __restrict__ v_arr) {
    __shared__ __attribute__((aligned(16))) union {
        struct { u16 Ah[128*32], Al[128*32], Bh[128*32], Bl[128*32]; } g;
        struct { float us[4][64], vs[4][64]; } uv;
    } sm;
    int bx = blockIdx.x, t = threadIdx.x;
    if (bx >= 160) {
        int idx = bx - 160;
        int c = idx >> 3, jc = idx & 7;
        int g = t >> 6, lane = t & 63;
        int j = jc * 64 + lane;
        int n = cnt[c], o = offs[c];
        float ua = 0.f, va = 0.f;
        for (int p = g; p < n; p += 4) {
            int m = order[o + p];
            float wm = wv[m];
            float wi = wm * inv[m];
            float xv = x[(size_t)m * D_DIM + j];
            ua += wi * xv; va += wm * xv;
        }
        sm.uv.us[g][lane] = ua; sm.uv.vs[g][lane] = va;
        __syncthreads();
        if (g == 0) {
            u_arr[(size_t)c * D_DIM + j] = sm.uv.us[0][lane] + sm.uv.us[1][lane] + sm.uv.us[2][lane] + sm.uv.us[3][lane];
            v_arr[(size_t)c * D_DIM + j] = sm.uv.vs[0][lane] + sm.uv.vs[1][lane] + sm.uv.vs[2][lane] + sm.uv.vs[3][lane];
        }
        return;
    }
    int tile = bx % 10;
    int p = bx / 10;                    // 0..15
    int ti = tile < 4 ? 0 : (tile < 7 ? 1 : (tile < 9 ? 2 : 3));
    int tj = tile - (ti == 0 ? 0 : (ti == 1 ? 3 : (ti == 2 ? 5 : 6)));
    int i0 = ti << 7, j0 = tj << 7;
    bool diag = (ti == tj);
    int kb = p << 9;                    // K-chunk of 512
    int w = t >> 6, l = t & 63;
    int srow = t >> 2, scol = (t & 3) << 3;
    int lm = l & 15, lg = l >> 4;
    floatx4 acc[4][4];
    #pragma unroll
    for (int mi = 0; mi < 4; ++mi)
        #pragma unroll
        for (int ni = 0; ni < 4; ++ni) acc[mi][ni] = (floatx4){0.f,0.f,0.f,0.f};
    int d0 = srow * 32 + scol;
    int d1 = (64 + srow) * 32 + scol;
    const size_t ga0 = (size_t)(i0 + srow) * N_ROWS + kb + scol;
    const size_t ga1 = (size_t)(i0 + 64 + srow) * N_ROWS + kb + scol;
    const size_t gb0 = (size_t)(j0 + srow) * N_ROWS + kb + scol;
    const size_t gb1 = (size_t)(j0 + 64 + srow) * N_ROWS + kb + scol;
    const u16* Bhs = diag ? sm.g.Ah : sm.g.Bh;
    const u16* Bls = diag ? sm.g.Al : sm.g.Bl;
    for (int s = 0; s < 16; ++s) {
        int ks = s << 5;
        cp16(zth + ga0 + ks, sm.g.Ah + d0);
        cp16(zth + ga1 + ks, sm.g.Ah + d1);
        cp16(ztl + ga0 + ks, sm.g.Al + d0);
        cp16(ztl + ga1 + ks, sm.g.Al + d1);
        if (!diag) {
            cp16(zth + gb0 + ks, sm.g.Bh + d0);
            cp16(zth + gb1 + ks, sm.g.Bh + d1);
            cp16(ztl + gb0 + ks, sm.g.Bl + d0);
            cp16(ztl + gb1 + ks, sm.g.Bl + d1);
        }
        __syncthreads();
        short8 ah[4], al[4], bh[4], bl[4];
        #pragma unroll
        for (int mi = 0; mi < 4; ++mi) {
            int off = (((w & 1) << 6) + (mi << 4) + lm) * 32 + (lg << 3);
            ah[mi] = *(const short8*)&sm.g.Ah[off];
            al[mi] = *(const short8*)&sm.g.Al[off];
        }
        #pragma unroll
        for (int ni = 0; ni < 4; ++ni) {
            int off = (((w >> 1) << 6) + (ni << 4) + lm) * 32 + (lg << 3);
            bh[ni] = *(const short8*)&Bhs[off];
            bl[ni] = *(const short8*)&Bls[off];
        }
        #pragma unroll
        for (int mi = 0; mi < 4; ++mi)
            #pragma unroll
            for (int ni = 0; ni < 4; ++ni) {
                acc[mi][ni] = __builtin_amdgcn_mfma_f32_16x16x32_bf16(ah[mi], bh[ni], acc[mi][ni], 0, 0, 0);
                acc[mi][ni] = __builtin_amdgcn_mfma_f32_16x16x32_bf16(ah[mi], bl[ni], acc[mi][ni], 0, 0, 0);
                acc[mi][ni] = __builtin_amdgcn_mfma_f32_16x16x32_bf16(al[mi], bh[ni], acc[mi][ni], 0, 0, 0);
            }
        __syncthreads();
    }
    #pragma unroll
    for (int mi = 0; mi < 4; ++mi) {
        int row0 = i0 + ((w & 1) << 6) + (mi << 4) + (lg << 2);
        #pragma unroll
        for (int ni = 0; ni < 4; ++ni) {
            int col = j0 + ((w >> 1) << 6) + (ni << 4) + lm;
            #pragma unroll
            for (int r = 0; r < 4; ++r) {
                float val = acc[mi][ni][r];
                atomicAdd(&G[(size_t)(row0 + r) * D_DIM + col], val);
                if (!diag)
                    atomicAdd(&G[(size_t)col * D_DIM + (row0 + r)], val);
            }
        }
    }
}

// ===== kD: protos[c][j] = (v + u@G)/n -> out[0:51200) =====
__global__ __launch_bounds__(256) void kD(const float* __restrict__ u_arr,
        const float* __restrict__ v_arr, const int* __restrict__ cnt,
        const float* __restrict__ G, float* __restrict__ out) {
    __shared__ float ug[D_DIM];
    int c = blockIdx.x >> 1;
    int j = ((blockIdx.x & 1) << 8) + threadIdx.x;
    ug[threadIdx.x]       = u_arr[(size_t)c * D_DIM + threadIdx.x];
    ug[threadIdx.x + 256] = u_arr[(size_t)c * D_DIM + threadIdx.x + 256];
    __syncthreads();
    float acc = v_arr[(size_t)c * D_DIM + j];
    #pragma unroll 8
    for (int k = 0; k < D_DIM; ++k)
        acc += ug[k] * G[(size_t)k * D_DIM + j];
    int n = cnt[c];
    float s = (n > 0) ? 1.0f / (float)n : 0.0f;
    out[(size_t)c * D_DIM + j] = acc * s;
}

// ===== kE: inter[i,j,:] = proto[j] - proto[i]; 4 pairs/block =====
__global__ __launch_bounds__(256) void kE(const float* __restrict__ proto,
                                          float* __restrict__ inter) {
    int pair = blockIdx.x * 4 + (threadIdx.x >> 6);
    int i = pair / C_CLS;
    int j = pair - i * C_CLS;
    int d = (threadIdx.x & 63) << 3;
    float4 pj0 = *(const float4*)&proto[j * D_DIM + d];
    float4 pj1 = *(const float4*)&proto[j * D_DIM + d + 4];
    float4 pi0 = *(const float4*)&proto[i * D_DIM + d];
    float4 pi1 = *(const float4*)&proto[i * D_DIM + d + 4];
    float4 r0, r1;
    r0.x = pj0.x - pi0.x; r0.y = pj0.y - pi0.y; r0.z = pj0.z - pi0.z; r0.w = pj0.w - pi0.w;
    r1.x = pj1.x - pi1.x; r1.y = pj1.y - pi1.y; r1.z = pj1.z - pi1.z; r1.w = pj1.w - pi1.w;
    *(float4*)&inter[(size_t)pair * D_DIM + d]     = r0;
    *(float4*)&inter[(size_t)pair * D_DIM + d + 4] = r1;
}

extern "C" void kernel_launch(void* const* d_in, const int* in_sizes, int n_in,
                              void* d_out, int out_size, void* d_ws, size_t ws_size,
                              hipStream_t stream) {
    const float* x      = (const float*)d_in[0];   // [8192, 512]
    const float* logits = (const float*)d_in[1];   // [8192, 100]
    float* out = (float*)d_out;
    float* ws  = (float*)d_ws;
    float* G     = ws + WS_G;
    float* inv   = ws + WS_INV;
    float* wv    = ws + WS_WV;
    int*   cls   = (int*)(ws + WS_CLS);
    int*   cnt   = (int*)(ws + WS_CNT);
    int*   offs  = (int*)(ws + WS_OFFS);
    int*   order = (int*)(ws + WS_ORDER);
    float* u_arr = ws + WS_U;
    float* v_arr = ws + WS_V;
    u16* zth = (u16*)(ws + WS_ZTH);
    u16* ztl = (u16*)(ws + WS_ZTL);

    kA<<<2208, 256, 0, stream>>>(logits, x, wv, cls, inv, zth, ztl, G);
    kB<<<1, 256, 0, stream>>>(cls, cnt, offs, order);
    kC<<<960, 256, 0, stream>>>(zth, ztl, x, inv, wv, order, offs, cnt, G, u_arr, v_arr);
    kD<<<C_CLS * 2, 256, 0, stream>>>(u_arr, v_arr, cnt, G, out);
    kE<<<C_CLS * C_CLS / 4, 256, 0, stream>>>(out, out + C_CLS * D_DIM);
}

// Round 10
// 173.055 us; speedup vs baseline: 2.2186x; 1.0727x over previous
//
#include <hip/hip_runtime.h>
#include <math.h>

#define N_ROWS 8192
#define D_DIM  512
#define C_CLS  100

typedef unsigned short u16;
typedef unsigned int u32;
typedef __attribute__((ext_vector_type(8))) _Float16 half8;
typedef __attribute__((ext_vector_type(4))) float floatx4;

// ---------------- ws layout (float offsets), ~10 MB ----------------
#define WS_G      0              // 512*512 fp32 (atomic accumulated)
#define WS_INV    262144         // 8192
#define WS_WV     270336         // 8192
#define WS_CLS    278528         // 8192 (int)
#define WS_CNT    286720         // 128 (int)
#define WS_OFFS   286848         // 128 (int)
#define WS_ORDER  286976         // 8192 (int)
#define WS_U      295168         // 100*512
#define WS_V      346368         // 100*512
#define WS_ZTH    397568         // 512*8192 fp16 (2097152 floats worth)

typedef const __attribute__((address_space(1))) u32* gp32;
typedef __attribute__((address_space(3))) u32* lp32;
__device__ __forceinline__ void cp16(const u16* g, u16* l) {
    __builtin_amdgcn_global_load_lds((gp32)g, (lp32)l, 16, 0, 0);
}

__device__ __forceinline__ u16 f2h(float v) {
    _Float16 h = (_Float16)v;
    return *(u16*)&h;
}

// ===== kA: bx<1024 softmax(8 rows) | [1024,1280) norm+cvt+transpose | rest zero G
__global__ __launch_bounds__(256) void kA(const float* __restrict__ logits,
        const float* __restrict__ x, float* __restrict__ wv, int* __restrict__ cls,
        float* __restrict__ inv, u16* __restrict__ zth, float* __restrict__ G) {
    __shared__ float xs[32 * 516];      // 66 KB fp32 stripe
    __shared__ float ns[8][32];
    __shared__ float sv_s[32];
    int bx = blockIdx.x, t = threadIdx.x;
    if (bx < 1024) {
        // -------- softmax max/argmax/denom, one wave per row, 2 rows --------
        int lane = t & 63;
        int row0 = (bx << 3) + ((t >> 6) << 1);
        #pragma unroll
        for (int rr = 0; rr < 2; ++rr) {
            int row = row0 + rr;
            const float* lrow = logits + (size_t)row * C_CLS;
            float v1 = lrow[lane];
            bool has2 = (lane + 64) < C_CLS;
            float v2 = has2 ? lrow[lane + 64] : -INFINITY;
            float m; int idx;
            if (v2 > v1) { m = v2; idx = lane + 64; } else { m = v1; idx = lane; }
            #pragma unroll
            for (int off = 32; off >= 1; off >>= 1) {
                float om = __shfl_down(m, off);
                int   oi = __shfl_down(idx, off);
                if (om > m || (om == m && oi < idx)) { m = om; idx = oi; }
            }
            m = __shfl(m, 0);
            idx = __shfl(idx, 0);
            float s = expf(v1 - m) + (has2 ? expf(v2 - m) : 0.0f);
            #pragma unroll
            for (int off = 32; off >= 1; off >>= 1) s += __shfl_down(s, off);
            if (lane == 0) {
                wv[row] = 1.0f / s;
                cls[row] = idx;
            }
        }
        return;
    }
    if (bx >= 1280) {
        int i = ((bx - 1280) * 256 + t) * 32;
        float4 z = make_float4(0.f, 0.f, 0.f, 0.f);
        #pragma unroll
        for (int q = 0; q < 8; ++q) *(float4*)&G[i + q * 4] = z;
        return;
    }
    // -------- 32-row stripe: stage to LDS, norms, fp16 convert + transpose --
    int r0 = (bx - 1024) << 5;
    const float* src = x + (size_t)r0 * D_DIM;
    #pragma unroll
    for (int i = 0; i < 16; ++i) {
        int e = i * 1024 + t * 4;
        int r = e >> 9, c = e & 511;
        *(float4*)&xs[r * 516 + c] = *(const float4*)&src[e];
    }
    __syncthreads();
    {
        int r = t & 31, seg = t >> 5;
        const float* row = &xs[r * 516 + seg * 64];
        float ss = 0.f;
        #pragma unroll
        for (int jj = 0; jj < 64; ++jj) { float v = row[jj]; ss += v * v; }
        ns[seg][r] = ss;
    }
    __syncthreads();
    if (t < 32) {
        float ss = ns[0][t] + ns[1][t] + ns[2][t] + ns[3][t]
                 + ns[4][t] + ns[5][t] + ns[6][t] + ns[7][t];
        float iv = 1.0f / fmaxf(sqrtf(ss), 1e-8f);
        inv[r0 + t] = iv;
        sv_s[t] = sqrtf(iv);
    }
    __syncthreads();
    int c = t >> 2, rq = (t & 3) * 8;
    float svl[8];
    #pragma unroll
    for (int ii = 0; ii < 8; ++ii) svl[ii] = sv_s[rq + ii];
    #pragma unroll
    for (int ct = 0; ct < 8; ++ct) {
        int d = ct * 64 + c;
        u16 o[8];
        #pragma unroll
        for (int ii = 0; ii < 8; ++ii)
            o[ii] = f2h(xs[(rq + ii) * 516 + d] * svl[ii]);
        uint4 val = make_uint4((u32)o[0] | ((u32)o[1] << 16),
                               (u32)o[2] | ((u32)o[3] << 16),
                               (u32)o[4] | ((u32)o[5] << 16),
                               (u32)o[6] | ((u32)o[7] << 16));
        *(uint4*)&zth[(size_t)d * N_ROWS + r0 + rq] = val;
    }
}

// ===== kB: single-block class histogram + scan + scatter =====
__global__ __launch_bounds__(256) void kB(const int* __restrict__ cls,
        int* __restrict__ cnt, int* __restrict__ offs, int* __restrict__ order) {
    __shared__ int hist[128], scan_s[128], cur[128];
    int t = threadIdx.x;
    if (t < 128) hist[t] = 0;
    __syncthreads();
    for (int m = t; m < N_ROWS; m += 256) atomicAdd(&hist[cls[m]], 1);
    __syncthreads();
    if (t < 128) scan_s[t] = hist[t];
    __syncthreads();
    #pragma unroll
    for (int d = 1; d < 128; d <<= 1) {
        int add = (t < 128 && t >= d) ? scan_s[t - d] : 0;
        __syncthreads();
        if (t < 128) scan_s[t] += add;
        __syncthreads();
    }
    if (t < 128) {
        int off0 = scan_s[t] - hist[t];
        cur[t] = off0;
        offs[t] = off0;
        cnt[t] = hist[t];
    }
    __syncthreads();
    for (int m = t; m < N_ROWS; m += 256) {
        int p = atomicAdd(&cur[cls[m]], 1);
        order[p] = m;
    }
}

// ===== kC: blocks 0..159 fp16 GEMM (splitK=16, atomic G+mirror); 160..959 uv ==
__global__ __launch_bounds__(256) void kC(const u16* __restrict__ zth,
        const float* __restrict__ x, const float* __restrict__ inv,
        const float* __restrict__ wv, const int* __restrict__ order,
        const int* __restrict__ offs, const int* __restrict__ cnt,
        float* __restrict__ G, float* __restrict__ u_arr, float* __restrict__ v_arr) {
    __shared__ __attribute__((aligned(16))) union {
        struct { u16 Ah[128 * 32], Bh[128 * 32]; } g;      // 16 KB
        struct { float us[4][64], vs[4][64]; } uv;
    } sm;
    int bx = blockIdx.x, t = threadIdx.x;
    if (bx >= 160) {
        int idx = bx - 160;
        int c = idx >> 3, jc = idx & 7;
        int g = t >> 6, lane = t & 63;
        int j = jc * 64 + lane;
        int n = cnt[c], o = offs[c];
        float ua = 0.f, va = 0.f;
        for (int p = g; p < n; p += 4) {
            int m = order[o + p];
            float wm = wv[m];
            float wi = wm * inv[m];
            float xv = x[(size_t)m * D_DIM + j];
            ua += wi * xv; va += wm * xv;
        }
        sm.uv.us[g][lane] = ua; sm.uv.vs[g][lane] = va;
        __syncthreads();
        if (g == 0) {
            u_arr[(size_t)c * D_DIM + j] = sm.uv.us[0][lane] + sm.uv.us[1][lane] + sm.uv.us[2][lane] + sm.uv.us[3][lane];
            v_arr[(size_t)c * D_DIM + j] = sm.uv.vs[0][lane] + sm.uv.vs[1][lane] + sm.uv.vs[2][lane] + sm.uv.vs[3][lane];
        }
        return;
    }
    int tile = bx % 10;
    int p = bx / 10;                    // 0..15
    int ti = tile < 4 ? 0 : (tile < 7 ? 1 : (tile < 9 ? 2 : 3));
    int tj = tile - (ti == 0 ? 0 : (ti == 1 ? 3 : (ti == 2 ? 5 : 6)));
    int i0 = ti << 7, j0 = tj << 7;
    bool diag = (ti == tj);
    int kb = p << 9;                    // K-chunk of 512
    int w = t >> 6, l = t & 63;
    int srow = t >> 2, scol = (t & 3) << 3;
    int lm = l & 15, lg = l >> 4;
    floatx4 acc[4][4];
    #pragma unroll
    for (int mi = 0; mi < 4; ++mi)
        #pragma unroll
        for (int ni = 0; ni < 4; ++ni) acc[mi][ni] = (floatx4){0.f, 0.f, 0.f, 0.f};
    int d0 = srow * 32 + scol;
    int d1 = (64 + srow) * 32 + scol;
    const size_t ga0 = (size_t)(i0 + srow) * N_ROWS + kb + scol;
    const size_t ga1 = (size_t)(i0 + 64 + srow) * N_ROWS + kb + scol;
    const size_t gb0 = (size_t)(j0 + srow) * N_ROWS + kb + scol;
    const size_t gb1 = (size_t)(j0 + 64 + srow) * N_ROWS + kb + scol;
    const u16* Bhs = diag ? sm.g.Ah : sm.g.Bh;
    for (int s = 0; s < 16; ++s) {
        int ks = s << 5;
        cp16(zth + ga0 + ks, sm.g.Ah + d0);
        cp16(zth + ga1 + ks, sm.g.Ah + d1);
        if (!diag) {
            cp16(zth + gb0 + ks, sm.g.Bh + d0);
            cp16(zth + gb1 + ks, sm.g.Bh + d1);
        }
        __syncthreads();
        half8 ah[4], bh[4];
        #pragma unroll
        for (int mi = 0; mi < 4; ++mi) {
            int off = (((w & 1) << 6) + (mi << 4) + lm) * 32 + (lg << 3);
            ah[mi] = *(const half8*)&sm.g.Ah[off];
        }
        #pragma unroll
        for (int ni = 0; ni < 4; ++ni) {
            int off = (((w >> 1) << 6) + (ni << 4) + lm) * 32 + (lg << 3);
            bh[ni] = *(const half8*)&Bhs[off];
        }
        #pragma unroll
        for (int mi = 0; mi < 4; ++mi)
            #pragma unroll
            for (int ni = 0; ni < 4; ++ni)
                acc[mi][ni] = __builtin_amdgcn_mfma_f32_16x16x32_f16(ah[mi], bh[ni], acc[mi][ni], 0, 0, 0);
        __syncthreads();
    }
    #pragma unroll
    for (int mi = 0; mi < 4; ++mi) {
        int row0 = i0 + ((w & 1) << 6) + (mi << 4) + (lg << 2);
        #pragma unroll
        for (int ni = 0; ni < 4; ++ni) {
            int col = j0 + ((w >> 1) << 6) + (ni << 4) + lm;
            #pragma unroll
            for (int r = 0; r < 4; ++r) {
                float val = acc[mi][ni][r];
                atomicAdd(&G[(size_t)(row0 + r) * D_DIM + col], val);
                if (!diag)
                    atomicAdd(&G[(size_t)col * D_DIM + (row0 + r)], val);
            }
        }
    }
}

// ===== kD: protos, tiled for G-reuse: 13 class-groups x 16 col-panels =====
__global__ __launch_bounds__(256) void kD(const float* __restrict__ u_arr,
        const float* __restrict__ v_arr, const int* __restrict__ cnt,
        const float* __restrict__ G, float* __restrict__ out) {
    __shared__ float us[8][512];
    int g = blockIdx.x >> 4;            // 0..12
    int panel = blockIdx.x & 15;        // 0..15
    int t = threadIdx.x;
    for (int idx = t; idx < 8 * 512; idx += 256) {
        int ci = idx >> 9, k = idx & 511;
        int cc = g * 8 + ci;
        us[ci][k] = (cc < C_CLS) ? u_arr[(size_t)cc * D_DIM + k] : 0.f;
    }
    __syncthreads();
    int ci = t >> 5, cj = t & 31;
    int c = g * 8 + ci;
    int j = panel * 32 + cj;
    float acc = 0.f;
    #pragma unroll 8
    for (int k = 0; k < D_DIM; ++k)
        acc += us[ci][k] * G[(size_t)k * D_DIM + j];
    if (c < C_CLS) {
        int n = cnt[c];
        float s = (n > 0) ? 1.0f / (float)n : 0.0f;
        out[(size_t)c * D_DIM + j] = (v_arr[(size_t)c * D_DIM + j] + acc) * s;
    }
}

// ===== kE: inter[i,j,:] = proto[j] - proto[i]; 4 pairs/block =====
__global__ __launch_bounds__(256) void kE(const float* __restrict__ proto,
                                          float* __restrict__ inter) {
    int pair = blockIdx.x * 4 + (threadIdx.x >> 6);
    int i = pair / C_CLS;
    int j = pair - i * C_CLS;
    int d = (threadIdx.x & 63) << 3;
    float4 pj0 = *(const float4*)&proto[j * D_DIM + d];
    float4 pj1 = *(const float4*)&proto[j * D_DIM + d + 4];
    float4 pi0 = *(const float4*)&proto[i * D_DIM + d];
    float4 pi1 = *(const float4*)&proto[i * D_DIM + d + 4];
    float4 r0, r1;
    r0.x = pj0.x - pi0.x; r0.y = pj0.y - pi0.y; r0.z = pj0.z - pi0.z; r0.w = pj0.w - pi0.w;
    r1.x = pj1.x - pi1.x; r1.y = pj1.y - pi1.y; r1.z = pj1.z - pi1.z; r1.w = pj1.w - pi1.w;
    *(float4*)&inter[(size_t)pair * D_DIM + d]     = r0;
    *(float4*)&inter[(size_t)pair * D_DIM + d + 4] = r1;
}

extern "C" void kernel_launch(void* const* d_in, const int* in_sizes, int n_in,
                              void* d_out, int out_size, void* d_ws, size_t ws_size,
                              hipStream_t stream) {
    const float* x      = (const float*)d_in[0];   // [8192, 512]
    const float* logits = (const float*)d_in[1];   // [8192, 100]
    float* out = (float*)d_out;
    float* ws  = (float*)d_ws;
    float* G     = ws + WS_G;
    float* inv   = ws + WS_INV;
    float* wv    = ws + WS_WV;
    int*   cls   = (int*)(ws + WS_CLS);
    int*   cnt   = (int*)(ws + WS_CNT);
    int*   offs  = (int*)(ws + WS_OFFS);
    int*   order = (int*)(ws + WS_ORDER);
    float* u_arr = ws + WS_U;
    float* v_arr = ws + WS_V;
    u16* zth = (u16*)(ws + WS_ZTH);

    kA<<<1312, 256, 0, stream>>>(logits, x, wv, cls, inv, zth, G);
    kB<<<1, 256, 0, stream>>>(cls, cnt, offs, order);
    kC<<<960, 256, 0, stream>>>(zth, x, inv, wv, order, offs, cnt, G, u_arr, v_arr);
    kD<<<208, 256, 0, stream>>>(u_arr, v_arr, cnt, G, out);
    kE<<<C_CLS * C_CLS / 4, 256, 0, stream>>>(out, out + C_CLS * D_DIM);
}

// Round 11
// 169.641 us; speedup vs baseline: 2.2633x; 1.0201x over previous
//
#include <hip/hip_runtime.h>
#include <math.h>

#define N_ROWS 8192
#define D_DIM  512
#define C_CLS  100

typedef unsigned short u16;
typedef unsigned int u32;
typedef __attribute__((ext_vector_type(8))) _Float16 half8;
typedef __attribute__((ext_vector_type(4))) float floatx4;

// ---------------- ws layout (float offsets), ~20.5 MB ----------------
#define WS_G      0              // 512*512 fp32 (written by kR)
#define WS_GP     262144         // 16*10*16384 fp32 splitK partials
#define WS_INV    2883584        // 8192
#define WS_WV     2891776        // 8192
#define WS_CLS    2899968        // 8192 (int)
#define WS_CNT    2908160        // 128 (int)
#define WS_OFFS   2908288        // 128 (int)
#define WS_ORDER  2908416        // 8192 (int)
#define WS_U      2916608        // 100*512
#define WS_V      2967808        // 100*512
#define WS_ZTH    3019008        // 512*8192 fp16

typedef const __attribute__((address_space(1))) u32* gp32;
typedef __attribute__((address_space(3))) u32* lp32;
__device__ __forceinline__ void cp16(const u16* g, u16* l) {
    __builtin_amdgcn_global_load_lds((gp32)g, (lp32)l, 16, 0, 0);
}

__device__ __forceinline__ u16 f2h(float v) {
    _Float16 h = (_Float16)v;
    return *(u16*)&h;
}

// ===== kA: bx<1024 softmax (8 rows) | [1024,1280) norm+cvt+transpose =====
__global__ __launch_bounds__(256) void kA(const float* __restrict__ logits,
        const float* __restrict__ x, float* __restrict__ wv, int* __restrict__ cls,
        float* __restrict__ inv, u16* __restrict__ zth) {
    __shared__ float xs[32 * 516];      // 66 KB fp32 stripe
    __shared__ float ns[8][32];
    __shared__ float sv_s[32];
    int bx = blockIdx.x, t = threadIdx.x;
    if (bx < 1024) {
        int lane = t & 63;
        int row0 = (bx << 3) + ((t >> 6) << 1);
        #pragma unroll
        for (int rr = 0; rr < 2; ++rr) {
            int row = row0 + rr;
            const float* lrow = logits + (size_t)row * C_CLS;
            float v1 = lrow[lane];
            bool has2 = (lane + 64) < C_CLS;
            float v2 = has2 ? lrow[lane + 64] : -INFINITY;
            float m; int idx;
            if (v2 > v1) { m = v2; idx = lane + 64; } else { m = v1; idx = lane; }
            #pragma unroll
            for (int off = 32; off >= 1; off >>= 1) {
                float om = __shfl_down(m, off);
                int   oi = __shfl_down(idx, off);
                if (om > m || (om == m && oi < idx)) { m = om; idx = oi; }
            }
            m = __shfl(m, 0);
            idx = __shfl(idx, 0);
            float s = expf(v1 - m) + (has2 ? expf(v2 - m) : 0.0f);
            #pragma unroll
            for (int off = 32; off >= 1; off >>= 1) s += __shfl_down(s, off);
            if (lane == 0) {
                wv[row] = 1.0f / s;
                cls[row] = idx;
            }
        }
        return;
    }
    // -------- 32-row stripe: stage to LDS, norms, fp16 convert + transpose --
    int r0 = (bx - 1024) << 5;
    const float* src = x + (size_t)r0 * D_DIM;
    #pragma unroll
    for (int i = 0; i < 16; ++i) {
        int e = i * 1024 + t * 4;
        int r = e >> 9, c = e & 511;
        *(float4*)&xs[r * 516 + c] = *(const float4*)&src[e];
    }
    __syncthreads();
    {
        int r = t & 31, seg = t >> 5;
        const float* row = &xs[r * 516 + seg * 64];
        float ss = 0.f;
        #pragma unroll
        for (int jj = 0; jj < 64; ++jj) { float v = row[jj]; ss += v * v; }
        ns[seg][r] = ss;
    }
    __syncthreads();
    if (t < 32) {
        float ss = ns[0][t] + ns[1][t] + ns[2][t] + ns[3][t]
                 + ns[4][t] + ns[5][t] + ns[6][t] + ns[7][t];
        float iv = 1.0f / fmaxf(sqrtf(ss), 1e-8f);
        inv[r0 + t] = iv;
        sv_s[t] = sqrtf(iv);
    }
    __syncthreads();
    int c = t >> 2, rq = (t & 3) * 8;
    float svl[8];
    #pragma unroll
    for (int ii = 0; ii < 8; ++ii) svl[ii] = sv_s[rq + ii];
    #pragma unroll
    for (int ct = 0; ct < 8; ++ct) {
        int d = ct * 64 + c;
        u16 o[8];
        #pragma unroll
        for (int ii = 0; ii < 8; ++ii)
            o[ii] = f2h(xs[(rq + ii) * 516 + d] * svl[ii]);
        uint4 val = make_uint4((u32)o[0] | ((u32)o[1] << 16),
                               (u32)o[2] | ((u32)o[3] << 16),
                               (u32)o[4] | ((u32)o[5] << 16),
                               (u32)o[6] | ((u32)o[7] << 16));
        *(uint4*)&zth[(size_t)d * N_ROWS + r0 + rq] = val;
    }
}

// ===== kB: single-block class histogram + scan + scatter =====
__global__ __launch_bounds__(256) void kB(const int* __restrict__ cls,
        int* __restrict__ cnt, int* __restrict__ offs, int* __restrict__ order) {
    __shared__ int hist[128], scan_s[128], cur[128];
    int t = threadIdx.x;
    if (t < 128) hist[t] = 0;
    __syncthreads();
    for (int m = t; m < N_ROWS; m += 256) atomicAdd(&hist[cls[m]], 1);
    __syncthreads();
    if (t < 128) scan_s[t] = hist[t];
    __syncthreads();
    #pragma unroll
    for (int d = 1; d < 128; d <<= 1) {
        int add = (t < 128 && t >= d) ? scan_s[t - d] : 0;
        __syncthreads();
        if (t < 128) scan_s[t] += add;
        __syncthreads();
    }
    if (t < 128) {
        int off0 = scan_s[t] - hist[t];
        cur[t] = off0;
        offs[t] = off0;
        cnt[t] = hist[t];
    }
    __syncthreads();
    for (int m = t; m < N_ROWS; m += 256) {
        int p = atomicAdd(&cur[cls[m]], 1);
        order[p] = m;
    }
}

// ===== kC: blocks 0..159 fp16 GEMM (splitK=16, store partials); 160..959 uv ==
__global__ __launch_bounds__(256) void kC(const u16* __restrict__ zth,
        const float* __restrict__ x, const float* __restrict__ inv,
        const float* __restrict__ wv, const int* __restrict__ order,
        const int* __restrict__ offs, const int* __restrict__ cnt,
        float* __restrict__ Gp, float* __restrict__ u_arr, float* __restrict__ v_arr) {
    __shared__ __attribute__((aligned(16))) union {
        struct { u16 Ah[128 * 32], Bh[128 * 32]; } g;      // 16 KB
        struct { float us[4][64], vs[4][64]; } uv;
    } sm;
    int bx = blockIdx.x, t = threadIdx.x;
    if (bx >= 160) {
        int idx = bx - 160;
        int c = idx >> 3, jc = idx & 7;
        int g = t >> 6, lane = t & 63;
        int j = jc * 64 + lane;
        int n = cnt[c], o = offs[c];
        float ua = 0.f, va = 0.f;
        for (int p = g; p < n; p += 4) {
            int m = order[o + p];
            float wm = wv[m];
            float wi = wm * inv[m];
            float xv = x[(size_t)m * D_DIM + j];
            ua += wi * xv; va += wm * xv;
        }
        sm.uv.us[g][lane] = ua; sm.uv.vs[g][lane] = va;
        __syncthreads();
        if (g == 0) {
            u_arr[(size_t)c * D_DIM + j] = sm.uv.us[0][lane] + sm.uv.us[1][lane] + sm.uv.us[2][lane] + sm.uv.us[3][lane];
            v_arr[(size_t)c * D_DIM + j] = sm.uv.vs[0][lane] + sm.uv.vs[1][lane] + sm.uv.vs[2][lane] + sm.uv.vs[3][lane];
        }
        return;
    }
    int tile = bx % 10;
    int p = bx / 10;                    // 0..15
    int ti = tile < 4 ? 0 : (tile < 7 ? 1 : (tile < 9 ? 2 : 3));
    int tj = tile - (ti == 0 ? 0 : (ti == 1 ? 3 : (ti == 2 ? 5 : 6)));
    int i0 = ti << 7, j0 = tj << 7;
    bool diag = (ti == tj);
    int kb = p << 9;                    // K-chunk of 512
    int w = t >> 6, l = t & 63;
    int srow = t >> 2, scol = (t & 3) << 3;
    int lm = l & 15, lg = l >> 4;
    floatx4 acc[4][4];
    #pragma unroll
    for (int mi = 0; mi < 4; ++mi)
        #pragma unroll
        for (int ni = 0; ni < 4; ++ni) acc[mi][ni] = (floatx4){0.f, 0.f, 0.f, 0.f};
    int d0 = srow * 32 + scol;
    int d1 = (64 + srow) * 32 + scol;
    const size_t ga0 = (size_t)(i0 + srow) * N_ROWS + kb + scol;
    const size_t ga1 = (size_t)(i0 + 64 + srow) * N_ROWS + kb + scol;
    const size_t gb0 = (size_t)(j0 + srow) * N_ROWS + kb + scol;
    const size_t gb1 = (size_t)(j0 + 64 + srow) * N_ROWS + kb + scol;
    const u16* Bhs = diag ? sm.g.Ah : sm.g.Bh;
    for (int s = 0; s < 16; ++s) {
        int ks = s << 5;
        cp16(zth + ga0 + ks, sm.g.Ah + d0);
        cp16(zth + ga1 + ks, sm.g.Ah + d1);
        if (!diag) {
            cp16(zth + gb0 + ks, sm.g.Bh + d0);
            cp16(zth + gb1 + ks, sm.g.Bh + d1);
        }
        __syncthreads();
        half8 ah[4], bh[4];
        #pragma unroll
        for (int mi = 0; mi < 4; ++mi) {
            int off = (((w & 1) << 6) + (mi << 4) + lm) * 32 + (lg << 3);
            ah[mi] = *(const half8*)&sm.g.Ah[off];
        }
        #pragma unroll
        for (int ni = 0; ni < 4; ++ni) {
            int off = (((w >> 1) << 6) + (ni << 4) + lm) * 32 + (lg << 3);
            bh[ni] = *(const half8*)&Bhs[off];
        }
        #pragma unroll
        for (int mi = 0; mi < 4; ++mi)
            #pragma unroll
            for (int ni = 0; ni < 4; ++ni)
                acc[mi][ni] = __builtin_amdgcn_mfma_f32_16x16x32_f16(ah[mi], bh[ni], acc[mi][ni], 0, 0, 0);
        __syncthreads();
    }
    float* Gb = Gp + ((size_t)(p * 10 + tile) << 14);
    #pragma unroll
    for (int mi = 0; mi < 4; ++mi) {
        int row0 = ((w & 1) << 6) + (mi << 4) + (lg << 2);
        #pragma unroll
        for (int ni = 0; ni < 4; ++ni) {
            int col = ((w >> 1) << 6) + (ni << 4) + lm;
            #pragma unroll
            for (int r = 0; r < 4; ++r)
                Gb[(size_t)(row0 + r) * 128 + col] = acc[mi][ni][r];
        }
    }
}

// ===== kR: G[r][c] = sum_p Gp[p][uppertile(r,c)] (mirror lower) =====
__global__ __launch_bounds__(256) void kR(const float* __restrict__ Gp,
                                          float* __restrict__ G) {
    int i = blockIdx.x * 256 + threadIdx.x;      // 0..262143
    int r = i >> 9, c = i & 511;
    int tr = r >> 7, tc = c >> 7, rr = r & 127, cc = c & 127;
    if (tr > tc) { int tmp = tr; tr = tc; tc = tmp; tmp = rr; rr = cc; cc = tmp; }
    int tid = tr * 4 + tc - ((tr * (tr + 1)) >> 1);
    const float* src = Gp + ((size_t)tid << 14) + rr * 128 + cc;
    float s = 0.f;
    #pragma unroll
    for (int p = 0; p < 16; ++p) s += src[(size_t)p * 163840];
    G[i] = s;
}

// ===== kD: protos, tiled for G-reuse: 13 class-groups x 16 col-panels =====
__global__ __launch_bounds__(256) void kD(const float* __restrict__ u_arr,
        const float* __restrict__ v_arr, const int* __restrict__ cnt,
        const float* __restrict__ G, float* __restrict__ out) {
    __shared__ float us[8][512];
    int g = blockIdx.x >> 4;            // 0..12
    int panel = blockIdx.x & 15;        // 0..15
    int t = threadIdx.x;
    for (int idx = t; idx < 8 * 512; idx += 256) {
        int ci = idx >> 9, k = idx & 511;
        int cc = g * 8 + ci;
        us[ci][k] = (cc < C_CLS) ? u_arr[(size_t)cc * D_DIM + k] : 0.f;
    }
    __syncthreads();
    int ci = t >> 5, cj = t & 31;
    int c = g * 8 + ci;
    int j = panel * 32 + cj;
    float acc = 0.f;
    #pragma unroll 8
    for (int k = 0; k < D_DIM; ++k)
        acc += us[ci][k] * G[(size_t)k * D_DIM + j];
    if (c < C_CLS) {
        int n = cnt[c];
        float s = (n > 0) ? 1.0f / (float)n : 0.0f;
        out[(size_t)c * D_DIM + j] = (v_arr[(size_t)c * D_DIM + j] + acc) * s;
    }
}

// ===== kE: inter[i,j,:] = proto[j] - proto[i]; 4 pairs/block =====
__global__ __launch_bounds__(256) void kE(const float* __restrict__ proto,
                                          float* __restrict__ inter) {
    int pair = blockIdx.x * 4 + (threadIdx.x >> 6);
    int i = pair / C_CLS;
    int j = pair - i * C_CLS;
    int d = (threadIdx.x & 63) << 3;
    float4 pj0 = *(const float4*)&proto[j * D_DIM + d];
    float4 pj1 = *(const float4*)&proto[j * D_DIM + d + 4];
    float4 pi0 = *(const float4*)&proto[i * D_DIM + d];
    float4 pi1 = *(const float4*)&proto[i * D_DIM + d + 4];
    float4 r0, r1;
    r0.x = pj0.x - pi0.x; r0.y = pj0.y - pi0.y; r0.z = pj0.z - pi0.z; r0.w = pj0.w - pi0.w;
    r1.x = pj1.x - pi1.x; r1.y = pj1.y - pi1.y; r1.z = pj1.z - pi1.z; r1.w = pj1.w - pi1.w;
    *(float4*)&inter[(size_t)pair * D_DIM + d]     = r0;
    *(float4*)&inter[(size_t)pair * D_DIM + d + 4] = r1;
}

extern "C" void kernel_launch(void* const* d_in, const int* in_sizes, int n_in,
                              void* d_out, int out_size, void* d_ws, size_t ws_size,
                              hipStream_t stream) {
    const float* x      = (const float*)d_in[0];   // [8192, 512]
    const float* logits = (const float*)d_in[1];   // [8192, 100]
    float* out = (float*)d_out;
    float* ws  = (float*)d_ws;
    float* G     = ws + WS_G;
    float* Gp    = ws + WS_GP;
    float* inv   = ws + WS_INV;
    float* wv    = ws + WS_WV;
    int*   cls   = (int*)(ws + WS_CLS);
    int*   cnt   = (int*)(ws + WS_CNT);
    int*   offs  = (int*)(ws + WS_OFFS);
    int*   order = (int*)(ws + WS_ORDER);
    float* u_arr = ws + WS_U;
    float* v_arr = ws + WS_V;
    u16* zth = (u16*)(ws + WS_ZTH);

    kA<<<1280, 256, 0, stream>>>(logits, x, wv, cls, inv, zth);
    kB<<<1, 256, 0, stream>>>(cls, cnt, offs, order);
    kC<<<960, 256, 0, stream>>>(zth, x, inv, wv, order, offs, cnt, Gp, u_arr, v_arr);
    kR<<<1024, 256, 0, stream>>>(Gp, G);
    kD<<<208, 256, 0, stream>>>(u_arr, v_arr, cnt, G, out);
    kE<<<C_CLS * C_CLS / 4, 256, 0, stream>>>(out, out + C_CLS * D_DIM);
}